// Round 1
// baseline (172.007 us; speedup 1.0000x reference)
//
#include <hip/hip_runtime.h>
#include <hip/hip_bf16.h>

// Radon transform: x (4,1,384,384) f32 -> out (4,460,64) f32
// pad = 38, Hp = Wp = 460, N_ANGLES = 64.
// Padded image is zeros outside the 384x384 core, so we sample the original
// image with a bounds check instead of materializing the pad.

constexpr int IMG  = 384;
constexpr int PAD  = 38;
constexpr int P    = 460;   // Hp = Wp
constexpr int NA   = 64;    // angles
constexpr int NB   = 4;     // batch

__device__ __forceinline__ float samp(const float* __restrict__ img, int iy, int ix) {
    // (iy, ix) are padded-image coords; nonzero only inside [PAD, PAD+IMG)
    unsigned uy = (unsigned)(iy - PAD);
    unsigned ux = (unsigned)(ix - PAD);
    return (uy < (unsigned)IMG && ux < (unsigned)IMG) ? img[uy * IMG + ux] : 0.0f;
}

__global__ __launch_bounds__(256) void radon_kernel(const float* __restrict__ x,
                                                    float* __restrict__ out) {
    const int wid  = blockIdx.x * 4 + (threadIdx.x >> 6);   // wave id
    const int lane = threadIdx.x & 63;
    if (wid >= NB * NA * P) return;

    // wid = (b*NA + a)*P + y  -> 4 consecutive y's (same line family) per block
    const int y  = wid % P;
    const int ba = wid / P;
    const int a  = ba % NA;
    const int b  = ba / NA;

    // angles = linspace(0,180,65)[:-1] -> 2.8125*a exactly in fp32
    const float th = (2.8125f * (float)a) * 0.017453292519943295f;
    float s, c;
    __sincosf(th, &s, &c);

    const float ysy = (2.0f * (float)y + 1.0f) / 460.0f - 1.0f;
    const float* img = x + b * IMG * IMG;

    float acc = 0.0f;
    for (int xx = lane; xx < P; xx += 64) {
        const float xsx = (2.0f * (float)xx + 1.0f) / 460.0f - 1.0f;
        const float gx = c * xsx - s * ysy;
        const float gy = s * xsx + c * ysy;
        const float fix = ((gx + 1.0f) * 460.0f - 1.0f) * 0.5f;
        const float fiy = ((gy + 1.0f) * 460.0f - 1.0f) * 0.5f;
        const float ix0f = floorf(fix);
        const float iy0f = floorf(fiy);
        const float wx = fix - ix0f;
        const float wy = fiy - iy0f;
        const int ix0 = (int)ix0f;
        const int iy0 = (int)iy0f;

        const float v00 = samp(img, iy0,     ix0);
        const float v01 = samp(img, iy0,     ix0 + 1);
        const float v10 = samp(img, iy0 + 1, ix0);
        const float v11 = samp(img, iy0 + 1, ix0 + 1);

        acc += v00 * ((1.0f - wy) * (1.0f - wx))
             + v01 * ((1.0f - wy) * wx)
             + v10 * (wy * (1.0f - wx))
             + v11 * (wy * wx);
    }

    // wave-wide sum (64 lanes)
    #pragma unroll
    for (int off = 32; off; off >>= 1) acc += __shfl_xor(acc, off);

    if (lane == 0) {
        // out[b, y, a]
        out[(b * P + y) * NA + a] = acc / 460.0f;
    }
}

extern "C" void kernel_launch(void* const* d_in, const int* in_sizes, int n_in,
                              void* d_out, int out_size, void* d_ws, size_t ws_size,
                              hipStream_t stream) {
    const float* x = (const float*)d_in[0];
    float* out = (float*)d_out;

    const int total_waves = NB * NA * P;           // 117760
    const int blocks = (total_waves + 3) / 4;      // 4 waves / 256-thread block
    radon_kernel<<<blocks, 256, 0, stream>>>(x, out);
}

// Round 2
// 76.729 us; speedup vs baseline: 2.2417x; 2.2417x over previous
//
#include <hip/hip_runtime.h>
#include <hip/hip_bf16.h>

// Radon transform: x (4,1,384,384) f32 -> out (4,460,64) f32
// pad = 38, Hp = Wp = 460, N_ANGLES = 64.
//
// Strategy: build a zero-bordered copy of the image (border B_=6 px around the
// 384^2 core, extent 396^2) in d_ws, so the per-sample bilinear gather needs NO
// bounds checks (one index + 4 loads at immediate offsets). Per projection
// line, solve the xx-interval where the 2x2 stencil can touch the core and
// loop only there (the border absorbs the conservative slack).

constexpr int IMG = 384;
constexpr int PAD = 38;
constexpr int P   = 460;   // Hp = Wp
constexpr int NA  = 64;
constexpr int NB  = 4;
constexpr int B_  = 6;               // zero border in the staged buffer
constexpr int O_  = PAD - B_;        // 32  : padded-coord of buffer origin
constexpr int E_  = IMG + 2 * B_;    // 396 : buffer extent

__global__ __launch_bounds__(256) void pad_kernel(const float* __restrict__ x,
                                                  float* __restrict__ pb) {
    int idx = blockIdx.x * 256 + threadIdx.x;
    if (idx >= NB * E_ * E_) return;
    int b  = idx / (E_ * E_);
    int r  = idx - b * (E_ * E_);
    int iy = r / E_;
    int ix = r - iy * E_;
    int py = iy + O_ - PAD;          // core-relative pixel coords
    int px = ix + O_ - PAD;
    float v = ((unsigned)py < (unsigned)IMG && (unsigned)px < (unsigned)IMG)
                  ? x[(b * IMG + py) * IMG + px] : 0.0f;
    pb[idx] = v;
}

__global__ __launch_bounds__(256) void radon_kernel(const float* __restrict__ pb,
                                                    float* __restrict__ out) {
    const int wid  = blockIdx.x * 4 + (threadIdx.x >> 6);
    const int lane = threadIdx.x & 63;
    if (wid >= NB * NA * P) return;

    const int y  = wid % P;
    const int ba = wid / P;
    const int a  = ba % NA;
    const int b  = ba / NA;

    const float th = (2.8125f * (float)a) * 0.017453292519943295f;
    float s, c;
    __sincosf(th, &s, &c);
    const float ys = (2.0f * (float)y + 1.0f) / 460.0f - 1.0f;

    // fix = c*xx + A ; fiy = s*xx + By   (padded-image pixel coords)
    const float A  = fmaf(-s, ys, 1.0f) * 230.0f - 0.5f - 229.5f * c;
    const float By = fmaf( c, ys, 1.0f) * 230.0f - 0.5f - 229.5f * s;

    // xx-interval where the 2x2 stencil can touch the core:
    // need fix in [37,423) and fiy in [37,423); use [36,424] conservative.
    float lo = 0.0f, hi = 459.0f;
    if (fabsf(c) > 1e-5f) {
        float t0 = (36.0f - A) / c, t1 = (424.0f - A) / c;
        lo = fmaxf(lo, fminf(t0, t1)); hi = fminf(hi, fmaxf(t0, t1));
    } else if (A < 36.0f || A > 424.0f) { lo = 500.0f; hi = -500.0f; }
    if (fabsf(s) > 1e-5f) {
        float t0 = (36.0f - By) / s, t1 = (424.0f - By) / s;
        lo = fmaxf(lo, fminf(t0, t1)); hi = fminf(hi, fmaxf(t0, t1));
    } else if (By < 36.0f || By > 424.0f) { lo = 500.0f; hi = -500.0f; }

    const int xlo = max(0,     (int)floorf(lo) - 1);
    const int xhi = min(P - 1, (int)ceilf(hi)  + 1);

    const float* __restrict__ img = pb + b * E_ * E_;
    float acc = 0.0f;
    for (int xx = xlo + lane; xx <= xhi; xx += 64) {
        const float xxf  = (float)xx;
        const float fix  = fmaf(c, xxf, A);
        const float fiy  = fmaf(s, xxf, By);
        const float ix0f = floorf(fix);
        const float iy0f = floorf(fiy);
        const float wx   = fix - ix0f;
        const float wy   = fiy - iy0f;
        // buffer index: (iy0-O_)*E_ + (ix0-O_); iy0f*E_+ix0f < 2^24 so exact
        const int idx = (int)fmaf(iy0f, (float)E_, ix0f) - (O_ * E_ + O_);
        const float* p = img + idx;
        const float v00 = p[0];
        const float v01 = p[1];
        const float v10 = p[E_];
        const float v11 = p[E_ + 1];
        const float top = fmaf(wx, v01 - v00, v00);
        const float bot = fmaf(wx, v11 - v10, v10);
        acc += fmaf(wy, bot - top, top);
    }

    #pragma unroll
    for (int off = 32; off; off >>= 1) acc += __shfl_xor(acc, off);

    if (lane == 0) out[(b * P + y) * NA + a] = acc / 460.0f;
}

// Fallback (no workspace): bounds-checked sampling straight from the input.
__device__ __forceinline__ float samp(const float* __restrict__ img, int iy, int ix) {
    unsigned uy = (unsigned)(iy - PAD);
    unsigned ux = (unsigned)(ix - PAD);
    return (uy < (unsigned)IMG && ux < (unsigned)IMG) ? img[uy * IMG + ux] : 0.0f;
}

__global__ __launch_bounds__(256) void radon_fallback(const float* __restrict__ x,
                                                      float* __restrict__ out) {
    const int wid  = blockIdx.x * 4 + (threadIdx.x >> 6);
    const int lane = threadIdx.x & 63;
    if (wid >= NB * NA * P) return;
    const int y  = wid % P;
    const int ba = wid / P;
    const int a  = ba % NA;
    const int b  = ba / NA;
    const float th = (2.8125f * (float)a) * 0.017453292519943295f;
    float s, c;
    __sincosf(th, &s, &c);
    const float ysy = (2.0f * (float)y + 1.0f) / 460.0f - 1.0f;
    const float* img = x + b * IMG * IMG;
    float acc = 0.0f;
    for (int xx = lane; xx < P; xx += 64) {
        const float xsx = (2.0f * (float)xx + 1.0f) / 460.0f - 1.0f;
        const float gx = c * xsx - s * ysy;
        const float gy = s * xsx + c * ysy;
        const float fix = ((gx + 1.0f) * 460.0f - 1.0f) * 0.5f;
        const float fiy = ((gy + 1.0f) * 460.0f - 1.0f) * 0.5f;
        const float ix0f = floorf(fix);
        const float iy0f = floorf(fiy);
        const float wx = fix - ix0f;
        const float wy = fiy - iy0f;
        const int ix0 = (int)ix0f;
        const int iy0 = (int)iy0f;
        const float v00 = samp(img, iy0,     ix0);
        const float v01 = samp(img, iy0,     ix0 + 1);
        const float v10 = samp(img, iy0 + 1, ix0);
        const float v11 = samp(img, iy0 + 1, ix0 + 1);
        acc += v00 * ((1.0f - wy) * (1.0f - wx))
             + v01 * ((1.0f - wy) * wx)
             + v10 * (wy * (1.0f - wx))
             + v11 * (wy * wx);
    }
    #pragma unroll
    for (int off = 32; off; off >>= 1) acc += __shfl_xor(acc, off);
    if (lane == 0) out[(b * P + y) * NA + a] = acc / 460.0f;
}

extern "C" void kernel_launch(void* const* d_in, const int* in_sizes, int n_in,
                              void* d_out, int out_size, void* d_ws, size_t ws_size,
                              hipStream_t stream) {
    const float* x = (const float*)d_in[0];
    float* out = (float*)d_out;

    const size_t need = (size_t)NB * E_ * E_ * sizeof(float);
    const int total_waves = NB * NA * P;            // 117760
    const int blocks = (total_waves + 3) / 4;

    if (ws_size >= need) {
        float* pb = (float*)d_ws;
        const int pad_total  = NB * E_ * E_;
        const int pad_blocks = (pad_total + 255) / 256;
        pad_kernel<<<pad_blocks, 256, 0, stream>>>(x, pb);
        radon_kernel<<<blocks, 256, 0, stream>>>(pb, out);
    } else {
        radon_fallback<<<blocks, 256, 0, stream>>>(x, out);
    }
}